// Round 2
// baseline (132.548 us; speedup 1.0000x reference)
//
#include <hip/hip_runtime.h>

#define NROWS 8192
#define NCENT 4096
#define DIM   256

typedef short bf16x8 __attribute__((ext_vector_type(8)));
typedef float f32x4  __attribute__((ext_vector_type(4)));

// fp32 -> bf16 round-to-nearest-even (bit twiddle; data is normal, no NaN path)
__device__ inline unsigned short f2bf(float f) {
    unsigned u = __float_as_uint(f);
    unsigned r = (u + 0x7fffu + ((u >> 16) & 1u)) >> 16;
    return (unsigned short)r;
}

// ---------------------------------------------------------------------------
// Kernel 1: row norms. One wave per row (64 lanes x float4 = 256 elements).
// ws[0..8191] = ||x_n||^2 ; ws[8192..12287] = ||c_k||^2
// grid = 12288 rows / 4 waves-per-block = 3072 blocks   (R1 fix: was 48)
// ---------------------------------------------------------------------------
__global__ __launch_bounds__(256) void norms_kernel(const float* __restrict__ x,
                                                    const float* __restrict__ c,
                                                    float* __restrict__ ws) {
    int t    = threadIdx.x;
    int lane = t & 63;
    int gw   = blockIdx.x * 4 + (t >> 6);   // global wave id, 0..12287
    const float* src;
    float* dst;
    if (gw < NROWS) { src = x + (size_t)gw * DIM;           dst = ws + gw; }
    else            { src = c + (size_t)(gw - NROWS) * DIM; dst = ws + gw; }
    float4 v = ((const float4*)src)[lane];
    float s = v.x * v.x + v.y * v.y + v.z * v.z + v.w * v.w;
    #pragma unroll
    for (int m = 32; m; m >>= 1) s += __shfl_xor(s, m);
    if (lane == 0) *dst = s;
}

// ---------------------------------------------------------------------------
// Kernel 2: fused GEMM (bf16 MFMA) + RBF epilogue + per-row reduce + atomicAdd.
// Block tile: 64 rows of x  x  64 centers, BK=32, 4 waves (256 thr).
// Wave w owns rows 16w..16w+15 of the tile, all 64 center cols (4 MFMA tiles).
// LDS layout: [row][chunk] where chunk = 16B (8 bf16), phys_chunk =
//   chunk ^ ((row>>1)&3)  -> the 16-lane frag read is 2-way bank aliasing (free).
// ---------------------------------------------------------------------------
__global__ __launch_bounds__(256) void rbf_kernel(const float* __restrict__ x,
                                                  const float* __restrict__ cent,
                                                  const float* __restrict__ w,
                                                  const float* __restrict__ sigp,
                                                  const float* __restrict__ norms,
                                                  float* __restrict__ out) {
    __shared__ __align__(16) short xs[64 * 32];
    __shared__ __align__(16) short cs[64 * 32];

    const int t    = threadIdx.x;
    const int m0   = blockIdx.y * 64;   // x-row tile base
    const int n0   = blockIdx.x * 64;   // center tile base

    // ---- staging assignment: thread t -> (row srow, 8-float segment seg) ----
    const int srow   = t >> 2;          // 0..63
    const int seg    = t & 3;           // 0..3  (8 floats = one 16B bf16 chunk)
    const int pchunk = seg ^ ((srow >> 1) & 3);
    const int sidx   = srow * 32 + pchunk * 8;   // short index into LDS tile

    const float* xg = x    + (size_t)(m0 + srow) * DIM + seg * 8;
    const float* cg = cent + (size_t)(n0 + srow) * DIM + seg * 8;

    // ---- MFMA lane mapping ----
    const int lane = t & 63;
    const int wave = t >> 6;
    const int lr   = lane & 15;   // A-row / B-col / C-col within 16
    const int lg   = lane >> 4;   // k-group (A/B), row-quad (C)

    const int arow = 16 * wave + lr;
    const int aidx = arow * 32 + ((lg ^ ((arow >> 1) & 3)) * 8);

    f32x4 acc[4] = {f32x4{0,0,0,0}, f32x4{0,0,0,0}, f32x4{0,0,0,0}, f32x4{0,0,0,0}};

    for (int k0 = 0; k0 < DIM; k0 += 32) {
        // global loads (fp32) for this K-slab
        float4 f0 = *(const float4*)(xg + k0);
        float4 f1 = *(const float4*)(xg + k0 + 4);
        float4 g0 = *(const float4*)(cg + k0);
        float4 g1 = *(const float4*)(cg + k0 + 4);

        __syncthreads();   // previous iteration's LDS reads complete

        // convert + 16B store into swizzled LDS
        union { unsigned short s[8]; int4 v; } ux, uc;
        ux.s[0]=f2bf(f0.x); ux.s[1]=f2bf(f0.y); ux.s[2]=f2bf(f0.z); ux.s[3]=f2bf(f0.w);
        ux.s[4]=f2bf(f1.x); ux.s[5]=f2bf(f1.y); ux.s[6]=f2bf(f1.z); ux.s[7]=f2bf(f1.w);
        uc.s[0]=f2bf(g0.x); uc.s[1]=f2bf(g0.y); uc.s[2]=f2bf(g0.z); uc.s[3]=f2bf(g0.w);
        uc.s[4]=f2bf(g1.x); uc.s[5]=f2bf(g1.y); uc.s[6]=f2bf(g1.z); uc.s[7]=f2bf(g1.w);
        *(int4*)(xs + sidx) = ux.v;
        *(int4*)(cs + sidx) = uc.v;

        __syncthreads();

        bf16x8 a = *(const bf16x8*)(xs + aidx);
        #pragma unroll
        for (int bt = 0; bt < 4; ++bt) {
            const int brow = 16 * bt + lr;
            bf16x8 b = *(const bf16x8*)(cs + brow * 32 + ((lg ^ ((brow >> 1) & 3)) * 8));
            acc[bt] = __builtin_amdgcn_mfma_f32_16x16x32_bf16(a, b, acc[bt], 0, 0, 0);
        }
    }

    // ---- epilogue: phi = w * exp(-sigma*max(d2,0)), reduce over 64 cols ----
    const float sigma = sigp[0];
    const float* x2 = norms;
    const float* c2 = norms + NROWS;

    const int rbase = m0 + 16 * wave + lg * 4;   // 4 consecutive rows per lane
    float x2v[4];
    #pragma unroll
    for (int r = 0; r < 4; ++r) x2v[r] = x2[rbase + r];

    float rs[4] = {0.f, 0.f, 0.f, 0.f};
    #pragma unroll
    for (int bt = 0; bt < 4; ++bt) {
        const int col = n0 + 16 * bt + lr;
        const float c2v = c2[col];
        const float wv  = w[col];
        #pragma unroll
        for (int r = 0; r < 4; ++r) {
            float d2 = x2v[r] + c2v - 2.0f * acc[bt][r];
            d2 = fmaxf(d2, 0.0f);
            rs[r] += wv * __expf(-sigma * d2);
        }
    }
    // reduce across the 16 lanes that share the same rows (xor bits 0..3)
    #pragma unroll
    for (int r = 0; r < 4; ++r) {
        rs[r] += __shfl_xor(rs[r], 1);
        rs[r] += __shfl_xor(rs[r], 2);
        rs[r] += __shfl_xor(rs[r], 4);
        rs[r] += __shfl_xor(rs[r], 8);
    }
    if (lr == 0) {
        #pragma unroll
        for (int r = 0; r < 4; ++r) atomicAdd(&out[rbase + r], rs[r]);
    }
}

extern "C" void kernel_launch(void* const* d_in, const int* in_sizes, int n_in,
                              void* d_out, int out_size, void* d_ws, size_t ws_size,
                              hipStream_t stream) {
    const float* x    = (const float*)d_in[0];
    const float* cent = (const float*)d_in[1];
    const float* w    = (const float*)d_in[2];
    const float* sig  = (const float*)d_in[3];
    float* out   = (float*)d_out;
    float* norms = (float*)d_ws;   // 12288 floats = 48 KB

    hipMemsetAsync(d_out, 0, (size_t)out_size * sizeof(float), stream);
    norms_kernel<<<(NROWS + NCENT) / 4, 256, 0, stream>>>(x, cent, norms);
    rbf_kernel<<<dim3(NCENT / 64, NROWS / 64), 256, 0, stream>>>(x, cent, w, sig, norms, out);
}

// Round 3
// 104.927 us; speedup vs baseline: 1.2632x; 1.2632x over previous
//
#include <hip/hip_runtime.h>

#define NROWS 8192
#define NCENT 4096
#define DIM   256

#define AS1 __attribute__((address_space(1)))
#define AS3 __attribute__((address_space(3)))

typedef short bf16x8 __attribute__((ext_vector_type(8)));
typedef float f32x4  __attribute__((ext_vector_type(4)));

// fp32 -> bf16 round-to-nearest-even
__device__ inline unsigned short f2bf(float f) {
    unsigned u = __float_as_uint(f);
    return (unsigned short)((u + 0x7fffu + ((u >> 16) & 1u)) >> 16);
}

// ---------------------------------------------------------------------------
// Prepass: fp32 -> bf16 convert (row-major, unswizzled) + row norms.
// 4 waves/block, 4 rows/wave -> 16 rows/block, 768 blocks.
// ws layout: norms[12288] | xbf[8192*256] | cbf[4096*256]
// ---------------------------------------------------------------------------
__global__ __launch_bounds__(256) void prep_kernel(const float* __restrict__ x,
                                                   const float* __restrict__ c,
                                                   float* __restrict__ norms,
                                                   unsigned short* __restrict__ xbf,
                                                   unsigned short* __restrict__ cbf) {
    const int t = threadIdx.x, lane = t & 63;
    const int wbase = (blockIdx.x * 4 + (t >> 6)) * 4;   // first row of this wave
    #pragma unroll
    for (int rr = 0; rr < 4; ++rr) {
        const int gw = wbase + rr;                        // 0..12287
        const float* src;
        unsigned short* dst;
        if (gw < NROWS) { src = x + (size_t)gw * DIM;           dst = xbf + (size_t)gw * DIM; }
        else            { src = c + (size_t)(gw - NROWS) * DIM; dst = cbf + (size_t)(gw - NROWS) * DIM; }
        float4 v = ((const float4*)src)[lane];
        ushort4 b;
        b.x = f2bf(v.x); b.y = f2bf(v.y); b.z = f2bf(v.z); b.w = f2bf(v.w);
        ((ushort4*)dst)[lane] = b;
        float s = v.x * v.x + v.y * v.y + v.z * v.z + v.w * v.w;
        #pragma unroll
        for (int m = 32; m; m >>= 1) s += __shfl_xor(s, m);
        if (lane == 0) norms[gw] = s;
    }
}

// ---------------------------------------------------------------------------
// Main kernel: 128x128 block tile, BK=32, 4 waves in 2x2 wave grid,
// 4x4 MFMA (16x16x32 bf16) tiles per wave. global_load_lds width-16 staging.
// LDS logical layout: row-major [row][32 bf16], 64 B/row; chunk (16 B) at
// physical position p holds logical chunk p ^ ((row>>1)&3)  -> frag reads are
// 2-way bank aliasing (free, m136). Swizzle applied via staging SOURCE addr
// (global_load_lds dest is forced lane-contiguous, m104/m108).
// ---------------------------------------------------------------------------
__global__ __launch_bounds__(256) void rbf_mfma(const unsigned short* __restrict__ xbf,
                                                const unsigned short* __restrict__ cbf,
                                                const float* __restrict__ w,
                                                const float* __restrict__ sigp,
                                                const float* __restrict__ norms,
                                                float* __restrict__ out) {
    __shared__ __align__(16) short As[128 * 32];
    __shared__ __align__(16) short Bs[128 * 32];

    const int t    = threadIdx.x;
    const int wave = t >> 6, lane = t & 63;
    const int m0   = blockIdx.y * 128;
    const int n0   = blockIdx.x * 128;
    const int wy   = wave >> 1, wx = wave & 1;
    const int lr   = lane & 15;       // frag m/n index
    const int g    = lane >> 4;       // frag k-group

    // ---- staging: wave stages rows 32w..32w+31 of both tiles (2 issues ea) ----
    const int r_in = lane >> 2;                        // 0..15 within 16-row group
    const int c_l  = (lane & 3) ^ ((r_in >> 1) & 3);   // logical chunk for this lane
    const unsigned short* ga0 = xbf + (size_t)(m0 + 32 * wave + r_in) * DIM + c_l * 8;
    const unsigned short* ga1 = ga0 + 16 * DIM;
    const unsigned short* gb0 = cbf + (size_t)(n0 + 32 * wave + r_in) * DIM + c_l * 8;
    const unsigned short* gb1 = gb0 + 16 * DIM;
    short* la0 = As + (32 * wave) * 32;                // uniform dest base per wave
    short* la1 = la0 + 16 * 32;
    short* lb0 = Bs + (32 * wave) * 32;
    short* lb1 = lb0 + 16 * 32;

    // ---- fragment read offsets (shorts) ----
    int aoff[4], boff[4];
    #pragma unroll
    for (int i = 0; i < 4; ++i) {
        int r = 64 * wy + 16 * i + lr;
        aoff[i] = r * 32 + ((g ^ ((r >> 1) & 3)) * 8);
    }
    #pragma unroll
    for (int j = 0; j < 4; ++j) {
        int r = 64 * wx + 16 * j + lr;
        boff[j] = r * 32 + ((g ^ ((r >> 1) & 3)) * 8);
    }

    f32x4 acc[4][4];
    #pragma unroll
    for (int i = 0; i < 4; ++i)
        #pragma unroll
        for (int j = 0; j < 4; ++j) acc[i][j] = f32x4{0, 0, 0, 0};

    #pragma unroll
    for (int kk = 0; kk < DIM / 32; ++kk) {
        __syncthreads();   // prior iter's ds_reads done before overwrite
        const int ko = kk * 32;
        __builtin_amdgcn_global_load_lds((const AS1 void*)(ga0 + ko), (AS3 void*)la0, 16, 0, 0);
        __builtin_amdgcn_global_load_lds((const AS1 void*)(ga1 + ko), (AS3 void*)la1, 16, 0, 0);
        __builtin_amdgcn_global_load_lds((const AS1 void*)(gb0 + ko), (AS3 void*)lb0, 16, 0, 0);
        __builtin_amdgcn_global_load_lds((const AS1 void*)(gb1 + ko), (AS3 void*)lb1, 16, 0, 0);
        __syncthreads();   // compiler drains vmcnt(0) before barrier

        bf16x8 a[4], b[4];
        #pragma unroll
        for (int i = 0; i < 4; ++i) a[i] = *(const bf16x8*)(As + aoff[i]);
        #pragma unroll
        for (int j = 0; j < 4; ++j) b[j] = *(const bf16x8*)(Bs + boff[j]);
        #pragma unroll
        for (int i = 0; i < 4; ++i)
            #pragma unroll
            for (int j = 0; j < 4; ++j)
                acc[i][j] = __builtin_amdgcn_mfma_f32_16x16x32_bf16(a[i], b[j], acc[i][j], 0, 0, 0);
    }

    // ---- epilogue: phi = w*exp(-sigma*max(d2,0)); reduce 64 cols per row ----
    const float sigma = sigp[0];
    const float* x2 = norms;
    const float* c2 = norms + NROWS;

    float c2v[4], wv[4];
    #pragma unroll
    for (int j = 0; j < 4; ++j) {
        int n = n0 + 64 * wx + 16 * j + lr;
        c2v[j] = c2[n];
        wv[j]  = w[n];
    }

    #pragma unroll
    for (int i = 0; i < 4; ++i) {
        const int mbase = m0 + 64 * wy + 16 * i + 4 * g;   // 4 consecutive rows
        float4 x2v = *(const float4*)(x2 + mbase);
        float rs[4] = {0.f, 0.f, 0.f, 0.f};
        #pragma unroll
        for (int j = 0; j < 4; ++j) {
            #pragma unroll
            for (int r = 0; r < 4; ++r) {
                float x2r = (r == 0) ? x2v.x : (r == 1) ? x2v.y : (r == 2) ? x2v.z : x2v.w;
                float d2 = x2r + c2v[j] - 2.0f * acc[i][j][r];
                d2 = fmaxf(d2, 0.0f);
                rs[r] += wv[j] * __expf(-sigma * d2);
            }
        }
        #pragma unroll
        for (int r = 0; r < 4; ++r) {
            rs[r] += __shfl_xor(rs[r], 1);
            rs[r] += __shfl_xor(rs[r], 2);
            rs[r] += __shfl_xor(rs[r], 4);
            rs[r] += __shfl_xor(rs[r], 8);
        }
        if (lr == 0) {
            #pragma unroll
            for (int r = 0; r < 4; ++r) atomicAdd(&out[mbase + r], rs[r]);
        }
    }
}

// ---------------------------------------------------------------------------
// Fallback (R2 kernels) if ws is too small for the bf16 scratch copies.
// ---------------------------------------------------------------------------
__global__ __launch_bounds__(256) void norms_kernel(const float* __restrict__ x,
                                                    const float* __restrict__ c,
                                                    float* __restrict__ ws) {
    int t = threadIdx.x, lane = t & 63;
    int gw = blockIdx.x * 4 + (t >> 6);
    const float* src;
    float* dst;
    if (gw < NROWS) { src = x + (size_t)gw * DIM;           dst = ws + gw; }
    else            { src = c + (size_t)(gw - NROWS) * DIM; dst = ws + gw; }
    float4 v = ((const float4*)src)[lane];
    float s = v.x * v.x + v.y * v.y + v.z * v.z + v.w * v.w;
    #pragma unroll
    for (int m = 32; m; m >>= 1) s += __shfl_xor(s, m);
    if (lane == 0) *dst = s;
}

__global__ __launch_bounds__(256) void rbf_kernel(const float* __restrict__ x,
                                                  const float* __restrict__ cent,
                                                  const float* __restrict__ w,
                                                  const float* __restrict__ sigp,
                                                  const float* __restrict__ norms,
                                                  float* __restrict__ out) {
    __shared__ __align__(16) short xs[64 * 32];
    __shared__ __align__(16) short cs[64 * 32];
    const int t = threadIdx.x;
    const int m0 = blockIdx.y * 64, n0 = blockIdx.x * 64;
    const int srow = t >> 2, seg = t & 3;
    const int pchunk = seg ^ ((srow >> 1) & 3);
    const int sidx = srow * 32 + pchunk * 8;
    const float* xg = x    + (size_t)(m0 + srow) * DIM + seg * 8;
    const float* cg = cent + (size_t)(n0 + srow) * DIM + seg * 8;
    const int lane = t & 63, wave = t >> 6;
    const int lr = lane & 15, lg = lane >> 4;
    const int arow = 16 * wave + lr;
    const int aidx = arow * 32 + ((lg ^ ((arow >> 1) & 3)) * 8);
    f32x4 acc[4] = {f32x4{0,0,0,0}, f32x4{0,0,0,0}, f32x4{0,0,0,0}, f32x4{0,0,0,0}};
    for (int k0 = 0; k0 < DIM; k0 += 32) {
        float4 f0 = *(const float4*)(xg + k0);
        float4 f1 = *(const float4*)(xg + k0 + 4);
        float4 g0 = *(const float4*)(cg + k0);
        float4 g1 = *(const float4*)(cg + k0 + 4);
        __syncthreads();
        union { unsigned short s[8]; int4 v; } ux, uc;
        ux.s[0]=f2bf(f0.x); ux.s[1]=f2bf(f0.y); ux.s[2]=f2bf(f0.z); ux.s[3]=f2bf(f0.w);
        ux.s[4]=f2bf(f1.x); ux.s[5]=f2bf(f1.y); ux.s[6]=f2bf(f1.z); ux.s[7]=f2bf(f1.w);
        uc.s[0]=f2bf(g0.x); uc.s[1]=f2bf(g0.y); uc.s[2]=f2bf(g0.z); uc.s[3]=f2bf(g0.w);
        uc.s[4]=f2bf(g1.x); uc.s[5]=f2bf(g1.y); uc.s[6]=f2bf(g1.z); uc.s[7]=f2bf(g1.w);
        *(int4*)(xs + sidx) = ux.v;
        *(int4*)(cs + sidx) = uc.v;
        __syncthreads();
        bf16x8 a = *(const bf16x8*)(xs + aidx);
        #pragma unroll
        for (int bt = 0; bt < 4; ++bt) {
            const int brow = 16 * bt + lr;
            bf16x8 b = *(const bf16x8*)(cs + brow * 32 + ((lg ^ ((brow >> 1) & 3)) * 8));
            acc[bt] = __builtin_amdgcn_mfma_f32_16x16x32_bf16(a, b, acc[bt], 0, 0, 0);
        }
    }
    const float sigma = sigp[0];
    const float* x2 = norms;
    const float* c2 = norms + NROWS;
    const int rbase = m0 + 16 * wave + lg * 4;
    float x2v[4];
    #pragma unroll
    for (int r = 0; r < 4; ++r) x2v[r] = x2[rbase + r];
    float rs[4] = {0.f, 0.f, 0.f, 0.f};
    #pragma unroll
    for (int bt = 0; bt < 4; ++bt) {
        const int col = n0 + 16 * bt + lr;
        const float c2v = c2[col];
        const float wvv = w[col];
        #pragma unroll
        for (int r = 0; r < 4; ++r) {
            float d2 = x2v[r] + c2v - 2.0f * acc[bt][r];
            d2 = fmaxf(d2, 0.0f);
            rs[r] += wvv * __expf(-sigma * d2);
        }
    }
    #pragma unroll
    for (int r = 0; r < 4; ++r) {
        rs[r] += __shfl_xor(rs[r], 1);
        rs[r] += __shfl_xor(rs[r], 2);
        rs[r] += __shfl_xor(rs[r], 4);
        rs[r] += __shfl_xor(rs[r], 8);
    }
    if (lr == 0) {
        #pragma unroll
        for (int r = 0; r < 4; ++r) atomicAdd(&out[rbase + r], rs[r]);
    }
}

extern "C" void kernel_launch(void* const* d_in, const int* in_sizes, int n_in,
                              void* d_out, int out_size, void* d_ws, size_t ws_size,
                              hipStream_t stream) {
    const float* x    = (const float*)d_in[0];
    const float* cent = (const float*)d_in[1];
    const float* w    = (const float*)d_in[2];
    const float* sig  = (const float*)d_in[3];
    float* out = (float*)d_out;

    const size_t norms_elems = NROWS + NCENT;              // 12288 floats
    const size_t xbf_off  = norms_elems * sizeof(float);   // 48 KB
    const size_t cbf_off  = xbf_off + (size_t)NROWS * DIM * sizeof(unsigned short);
    const size_t ws_need  = cbf_off + (size_t)NCENT * DIM * sizeof(unsigned short);

    hipMemsetAsync(d_out, 0, (size_t)out_size * sizeof(float), stream);

    if (ws_size >= ws_need) {
        float* norms = (float*)d_ws;
        unsigned short* xbf = (unsigned short*)((char*)d_ws + xbf_off);
        unsigned short* cbf = (unsigned short*)((char*)d_ws + cbf_off);
        prep_kernel<<<(NROWS + NCENT) / 16, 256, 0, stream>>>(x, cent, norms, xbf, cbf);
        rbf_mfma<<<dim3(NCENT / 128, NROWS / 128), 256, 0, stream>>>(xbf, cbf, w, sig, norms, out);
    } else {
        float* norms = (float*)d_ws;
        norms_kernel<<<(NROWS + NCENT) / 4, 256, 0, stream>>>(x, cent, norms);
        rbf_kernel<<<dim3(NCENT / 64, NROWS / 64), 256, 0, stream>>>(x, cent, w, sig, norms, out);
    }
}